// Round 1
// baseline (2680.077 us; speedup 1.0000x reference)
//
#include <hip/hip_runtime.h>
#include <hip/hip_bf16.h>
#include <math.h>

#define H 6
#define DH 64
#define D 384
#define L 16

__device__ __forceinline__ float geluf(float x) {
  return 0.5f * x * (1.0f + erff(x * 0.70710678118654752f));
}

__device__ __forceinline__ void atomicMaxF(float* addr, float val) {
  int old = __float_as_int(*addr);
  while (__int_as_float(old) < val) {
    int assumed = old;
    old = atomicCAS((int*)addr, assumed, __float_as_int(val));
    if (old == assumed) break;
  }
}

__global__ void fill_kernel(float* p, long n, float v) {
  long i = (long)blockIdx.x * blockDim.x + threadIdx.x;
  long stride = (long)gridDim.x * blockDim.x;
  for (; i < n; i += stride) p[i] = v;
}

// masked mean pool over L tokens then L2 normalize. one block per node, 384 threads.
__global__ void pool_norm_kernel(const float* __restrict__ tok, const int* __restrict__ ids,
                                 float* __restrict__ out, int N) {
  int n = blockIdx.x;
  int t = threadIdx.x;
  const float* tp = tok + (size_t)n * L * D;
  const int* ip = ids + (size_t)n * L;
  float s = 0.f;
  int cnt = 0;
#pragma unroll
  for (int l = 0; l < L; ++l) {
    int m = (ip[l] > 0);
    cnt += m;
    s += tp[(size_t)l * D + t] * (float)m;
  }
  float mean = s / fmaxf((float)cnt, 1e-9f);
  float v = mean * mean;
#pragma unroll
  for (int off = 32; off; off >>= 1) v += __shfl_down(v, off);
  __shared__ float part[D / 64];
  if ((t & 63) == 0) part[t >> 6] = v;
  __syncthreads();
  float tot = 0.f;
#pragma unroll
  for (int i = 0; i < D / 64; ++i) tot += part[i];
  float inv = 1.0f / fmaxf(sqrtf(tot), 1e-12f);
  out[(size_t)n * D + t] = mean * inv;
}

// C[M,384] = epilogue(act_in(A[M,384]) @ W[384,384] + bias)
// EPI: 0=none, 1=relu, 2=blend with xold via sigmoid(*skipPtr). GELU_IN: gelu on A load.
template <int EPI, bool GELU_IN>
__global__ __launch_bounds__(256) void gemm384_kernel(
    const float* __restrict__ A, const float* __restrict__ W,
    const float* __restrict__ bias, float* __restrict__ C, int M,
    const float* __restrict__ xold, const float* __restrict__ skipPtr) {
  __shared__ __align__(16) float As[16][68];
  __shared__ __align__(16) float Bs[16][68];
  int tid = threadIdx.x;
  int bm = blockIdx.x * 64, bn = blockIdx.y * 64;
  int tx = tid & 15, ty = tid >> 4;
  float acc[4][4] = {};
  for (int k0 = 0; k0 < D; k0 += 16) {
    int ar = tid >> 4, ac = tid & 15;
#pragma unroll
    for (int i = 0; i < 4; ++i) {
      int r = ar + i * 16;
      float a = (bm + r < M) ? A[(size_t)(bm + r) * D + k0 + ac] : 0.f;
      if (GELU_IN) a = geluf(a);
      As[ac][r] = a;
    }
    int br = tid >> 6, bc = tid & 63;
#pragma unroll
    for (int i = 0; i < 4; ++i)
      Bs[br + i * 4][bc] = W[(size_t)(k0 + br + i * 4) * D + bn + bc];
    __syncthreads();
#pragma unroll
    for (int kk = 0; kk < 16; ++kk) {
      float4 a4 = *(const float4*)&As[kk][ty * 4];
      float4 b4 = *(const float4*)&Bs[kk][tx * 4];
      float av[4] = {a4.x, a4.y, a4.z, a4.w};
      float bv[4] = {b4.x, b4.y, b4.z, b4.w};
#pragma unroll
      for (int i = 0; i < 4; ++i)
#pragma unroll
        for (int j = 0; j < 4; ++j) acc[i][j] += av[i] * bv[j];
    }
    __syncthreads();
  }
  float sa = 0.f;
  if (EPI == 2) sa = 1.0f / (1.0f + expf(-*skipPtr));
#pragma unroll
  for (int i = 0; i < 4; ++i) {
    int m = bm + ty * 4 + i;
    if (m >= M) continue;
#pragma unroll
    for (int j = 0; j < 4; ++j) {
      int n = bn + tx * 4 + j;
      float v = acc[i][j] + bias[n];
      if (EPI == 1) v = fmaxf(v, 0.f);
      if (EPI == 2) v = sa * v + (1.0f - sa) * xold[(size_t)m * D + n];
      C[(size_t)m * D + n] = v;
    }
  }
}

// tq[n,h,d] = sum_f A[h,d,f] * q[n,h,f]   (per-dest-node transform of q by a_rel)
__global__ void qtrans_kernel(const float* __restrict__ q, const float* __restrict__ A,
                              float* __restrict__ tq, int N) {
  int n = blockIdx.x, h = blockIdx.y, d = threadIdx.x;
  const float* Ah = A + (size_t)h * DH * DH + (size_t)d * DH;
  const float* qn = q + (size_t)n * D + h * DH;
  float s = 0.f;
#pragma unroll 16
  for (int f = 0; f < DH; ++f) s += Ah[f] * qn[f];
  tq[(size_t)n * D + h * DH + d] = s;
}

// vm[n,h,f] = sum_d v[n,h,d] * M[h,d,f]   (per-src-node transform of v by m_rel)
__global__ void vtrans_kernel(const float* __restrict__ v, const float* __restrict__ Mrel,
                              float* __restrict__ vm, int N) {
  int n = blockIdx.x, h = blockIdx.y, f = threadIdx.x;
  const float* Mh = Mrel + (size_t)h * DH * DH;
  const float* vn = v + (size_t)n * D + h * DH;
  float s = 0.f;
#pragma unroll 16
  for (int d0 = 0; d0 < DH; ++d0) s += vn[d0] * Mh[d0 * DH + f];
  vm[(size_t)n * D + h * DH + f] = s;
}

// one wave per edge: score[e,h] = (k[src,h,:]·tq[dst,h,:]) * p[h] / 8, atomicMax into mmax
__global__ void score_kernel(const float* __restrict__ k, const float* __restrict__ tq,
                             const int* __restrict__ src, const int* __restrict__ dst,
                             const float* __restrict__ prel, float* __restrict__ sc,
                             float* __restrict__ mmax, int E) {
  int w = blockIdx.x * (blockDim.x >> 6) + (threadIdx.x >> 6);
  int lane = threadIdx.x & 63;
  if (w >= E) return;
  int s = src[w], d = dst[w];
  const float* kp = k + (size_t)s * D;
  const float* tp = tq + (size_t)d * D;
  float pr[H];
#pragma unroll
  for (int h = 0; h < H; ++h) pr[h] = kp[h * DH + lane] * tp[h * DH + lane];
#pragma unroll
  for (int off = 32; off; off >>= 1) {
#pragma unroll
    for (int h = 0; h < H; ++h) pr[h] += __shfl_down(pr[h], off);
  }
  if (lane == 0) {
#pragma unroll
    for (int h = 0; h < H; ++h) {
      float v = pr[h] * prel[h] * 0.125f;
      sc[(size_t)w * H + h] = v;
      atomicMaxF(&mmax[(size_t)d * H + h], v);
    }
  }
}

__global__ void expsum_kernel(float* __restrict__ sc, const float* __restrict__ mmax,
                              float* __restrict__ den, const int* __restrict__ dst, long EH) {
  long i = (long)blockIdx.x * blockDim.x + threadIdx.x;
  if (i >= EH) return;
  int e = (int)(i / H), h = (int)(i % H);
  int d = dst[e];
  float ex = expf(sc[i] - mmax[(size_t)d * H + h]);
  sc[i] = ex;
  atomicAdd(&den[(size_t)d * H + h], ex);
}

// one wave per edge: agg[dst,h*64+f] += vm[src,h*64+f] * (ex/den)
__global__ void agg_kernel(const float* __restrict__ vm, const float* __restrict__ sc,
                           const float* __restrict__ den, const int* __restrict__ src,
                           const int* __restrict__ dst, float* __restrict__ agg, int E) {
  int w = blockIdx.x * (blockDim.x >> 6) + (threadIdx.x >> 6);
  int lane = threadIdx.x & 63;
  if (w >= E) return;
  int s = src[w], d = dst[w];
  float alpha[H];
#pragma unroll
  for (int h = 0; h < H; ++h) alpha[h] = sc[(size_t)w * H + h] / den[(size_t)d * H + h];
  const float* vp = vm + (size_t)s * D;
  float* ap = agg + (size_t)d * D;
#pragma unroll
  for (int h = 0; h < H; ++h) atomicAdd(&ap[h * DH + lane], vp[h * DH + lane] * alpha[h]);
}

extern "C" void kernel_launch(void* const* d_in, const int* in_sizes, int n_in,
                              void* d_out, int out_size, void* d_ws, size_t ws_size,
                              hipStream_t stream) {
  const float* tok_msg = (const float*)d_in[0];
  const float* tok_con = (const float*)d_in[1];
  const int* ids_msg = (const int*)d_in[2];
  const int* ids_con = (const int*)d_in[3];
  const int* src_cm = (const int*)d_in[4];
  const int* dst_cm = (const int*)d_in[5];
  const int* src_mc = (const int*)d_in[6];
  const int* dst_mc = (const int*)d_in[7];
  const float* lin_W = (const float*)d_in[8];
  const float* lin_b = (const float*)d_in[9];
  const float* kW = (const float*)d_in[10];
  const float* kb = (const float*)d_in[11];
  const float* qW = (const float*)d_in[12];
  const float* qb = (const float*)d_in[13];
  const float* vW = (const float*)d_in[14];
  const float* vb = (const float*)d_in[15];
  const float* aW = (const float*)d_in[16];
  const float* ab = (const float*)d_in[17];
  const float* a_rel = (const float*)d_in[18];
  const float* m_rel = (const float*)d_in[19];
  const float* p_rel = (const float*)d_in[20];
  const float* skip = (const float*)d_in[21];

  const int NM = in_sizes[2] / L;
  const int NC = in_sizes[3] / L;
  const int E = in_sizes[4];

  float* ws = (float*)d_ws;
  size_t off = 0;
  auto alloc = [&](size_t n) { float* p = ws + off; off += n; return p; };
  float* x0 = alloc((size_t)NM * D);
  float* x1 = alloc((size_t)NC * D);
  float* xn0 = alloc((size_t)NM * D);
  float* xn1 = alloc((size_t)NC * D);
  float* k0 = alloc((size_t)NM * D);
  float* k1 = alloc((size_t)NC * D);
  float* q0 = alloc((size_t)NM * D);
  float* q1 = alloc((size_t)NC * D);
  float* v0 = alloc((size_t)NM * D);
  float* v1 = alloc((size_t)NC * D);
  float* tq0 = alloc((size_t)NM * D);
  float* tq1 = alloc((size_t)NC * D);
  float* vm0 = alloc((size_t)NC * D);  // edge0 source = concept
  float* vm1 = alloc((size_t)NM * D);  // edge1 source = message
  float* agg0 = alloc((size_t)NM * D);
  float* agg1 = alloc((size_t)NC * D);
  float* sc = alloc((size_t)E * H);
  float* mmax = alloc((size_t)NC * H);
  float* den = alloc((size_t)NC * H);

  dim3 b256(256);
  auto gemmGrid = [](int M) { return dim3((M + 63) / 64, D / 64); };
  const size_t WSZ = (size_t)D * D;
  const size_t RSZ = (size_t)H * DH * DH;

  // pooling (agg buffers double as pooled scratch), then initial linear+relu
  pool_norm_kernel<<<NM, D, 0, stream>>>(tok_msg, ids_msg, agg0, NM);
  pool_norm_kernel<<<NC, D, 0, stream>>>(tok_con, ids_con, agg1, NC);
  gemm384_kernel<1, false><<<gemmGrid(NM), b256, 0, stream>>>(agg0, lin_W, lin_b, x0, NM, nullptr, nullptr);
  gemm384_kernel<1, false><<<gemmGrid(NC), b256, 0, stream>>>(agg1, lin_W + WSZ, lin_b + D, x1, NC, nullptr, nullptr);

  for (int l = 0; l < 2; ++l) {
    bool last = (l == 1);
    // projections (layer 2 only needs k_con, q_msg, v_con for output xs[0])
    gemm384_kernel<0, false><<<gemmGrid(NC), b256, 0, stream>>>(x1, kW + (l * 2 + 1) * WSZ, kb + (l * 2 + 1) * D, k1, NC, nullptr, nullptr);
    gemm384_kernel<0, false><<<gemmGrid(NM), b256, 0, stream>>>(x0, qW + (l * 2 + 0) * WSZ, qb + (l * 2 + 0) * D, q0, NM, nullptr, nullptr);
    gemm384_kernel<0, false><<<gemmGrid(NC), b256, 0, stream>>>(x1, vW + (l * 2 + 1) * WSZ, vb + (l * 2 + 1) * D, v1, NC, nullptr, nullptr);
    if (!last) {
      gemm384_kernel<0, false><<<gemmGrid(NM), b256, 0, stream>>>(x0, kW + (l * 2 + 0) * WSZ, kb + (l * 2 + 0) * D, k0, NM, nullptr, nullptr);
      gemm384_kernel<0, false><<<gemmGrid(NC), b256, 0, stream>>>(x1, qW + (l * 2 + 1) * WSZ, qb + (l * 2 + 1) * D, q1, NC, nullptr, nullptr);
      gemm384_kernel<0, false><<<gemmGrid(NM), b256, 0, stream>>>(x0, vW + (l * 2 + 0) * WSZ, vb + (l * 2 + 0) * D, v0, NM, nullptr, nullptr);
    }

    // ---- edge type 0: concept -> message ----
    qtrans_kernel<<<dim3(NM, H), DH, 0, stream>>>(q0, a_rel + (l * 2 + 0) * RSZ, tq0, NM);
    vtrans_kernel<<<dim3(NC, H), DH, 0, stream>>>(v1, m_rel + (l * 2 + 0) * RSZ, vm0, NC);
    fill_kernel<<<64, b256, 0, stream>>>(mmax, (long)NM * H, -INFINITY);
    fill_kernel<<<64, b256, 0, stream>>>(den, (long)NM * H, 0.f);
    fill_kernel<<<512, b256, 0, stream>>>(agg0, (long)NM * D, 0.f);
    score_kernel<<<(E + 3) / 4, b256, 0, stream>>>(k1, tq0, src_cm, dst_cm, p_rel + (l * 2 + 0) * H, sc, mmax, E);
    expsum_kernel<<<(int)(((long)E * H + 255) / 256), b256, 0, stream>>>(sc, mmax, den, dst_cm, (long)E * H);
    agg_kernel<<<(E + 3) / 4, b256, 0, stream>>>(vm0, sc, den, src_cm, dst_cm, agg0, E);
    float* out0 = last ? (float*)d_out : xn0;
    gemm384_kernel<2, true><<<gemmGrid(NM), b256, 0, stream>>>(agg0, aW + (l * 2 + 0) * WSZ, ab + (l * 2 + 0) * D, out0, NM, x0, skip + l * 2 + 0);

    if (!last) {
      // ---- edge type 1: message -> concept ----
      qtrans_kernel<<<dim3(NC, H), DH, 0, stream>>>(q1, a_rel + (l * 2 + 1) * RSZ, tq1, NC);
      vtrans_kernel<<<dim3(NM, H), DH, 0, stream>>>(v0, m_rel + (l * 2 + 1) * RSZ, vm1, NM);
      fill_kernel<<<64, b256, 0, stream>>>(mmax, (long)NC * H, -INFINITY);
      fill_kernel<<<64, b256, 0, stream>>>(den, (long)NC * H, 0.f);
      fill_kernel<<<512, b256, 0, stream>>>(agg1, (long)NC * D, 0.f);
      score_kernel<<<(E + 3) / 4, b256, 0, stream>>>(k0, tq1, src_mc, dst_mc, p_rel + (l * 2 + 1) * H, sc, mmax, E);
      expsum_kernel<<<(int)(((long)E * H + 255) / 256), b256, 0, stream>>>(sc, mmax, den, dst_mc, (long)E * H);
      agg_kernel<<<(E + 3) / 4, b256, 0, stream>>>(vm1, sc, den, src_mc, dst_mc, agg1, E);
      gemm384_kernel<2, true><<<gemmGrid(NC), b256, 0, stream>>>(agg1, aW + (l * 2 + 1) * WSZ, ab + (l * 2 + 1) * D, xn1, NC, x1, skip + l * 2 + 1);
      float* t;
      t = x0; x0 = xn0; xn0 = t;
      t = x1; x1 = xn1; xn1 = t;
    }
  }
}

// Round 2
// 1023.783 us; speedup vs baseline: 2.6178x; 2.6178x over previous
//
#include <hip/hip_runtime.h>
#include <math.h>

#define H 6
#define DH 64
#define D 384
#define L 16

typedef __attribute__((ext_vector_type(8))) short short8;
typedef __attribute__((ext_vector_type(4))) float f32x4;

__device__ __forceinline__ float bf2f(unsigned short u) {
  union { unsigned int i; float f; } x; x.i = ((unsigned int)u) << 16; return x.f;
}
__device__ __forceinline__ unsigned short f2bf(float f) {
  unsigned int x = __float_as_uint(f);
  x = x + 0x7fffu + ((x >> 16) & 1u);
  return (unsigned short)(x >> 16);
}
__device__ __forceinline__ float geluf(float x) {
  return 0.5f * x * (1.0f + erff(x * 0.70710678118654752f));
}

__global__ void fill_kernel(float* p, long n, float v) {
  long i = (long)blockIdx.x * blockDim.x + threadIdx.x;
  long stride = (long)gridDim.x * blockDim.x;
  for (; i < n; i += stride) p[i] = v;
}

// masked mean pool over L tokens then L2 normalize -> bf16. one block per node, 384 threads.
__global__ void pool_norm_kernel(const float* __restrict__ tok, const int* __restrict__ ids,
                                 unsigned short* __restrict__ out, int N) {
  int n = blockIdx.x;
  int t = threadIdx.x;
  const float* tp = tok + (size_t)n * L * D;
  const int* ip = ids + (size_t)n * L;
  float s = 0.f;
  int cnt = 0;
#pragma unroll
  for (int l = 0; l < L; ++l) {
    int m = (ip[l] > 0);
    cnt += m;
    s += tp[(size_t)l * D + t] * (float)m;
  }
  float mean = s / fmaxf((float)cnt, 1e-9f);
  float v = mean * mean;
#pragma unroll
  for (int off = 32; off; off >>= 1) v += __shfl_down(v, off);
  __shared__ float part[D / 64];
  if ((t & 63) == 0) part[t >> 6] = v;
  __syncthreads();
  float tot = 0.f;
#pragma unroll
  for (int i = 0; i < D / 64; ++i) tot += part[i];
  float inv = 1.0f / fmaxf(sqrtf(tot), 1e-12f);
  out[(size_t)n * D + t] = f2bf(mean * inv);
}

// transpose + convert: Wt[n][k] (bf16) = W[k][n] (fp32). grid (12,12), block (32,32)
__global__ void wtconv_kernel(const float* __restrict__ W, unsigned short* __restrict__ Wt) {
  __shared__ float t[32][33];
  int tx = threadIdx.x, ty = threadIdx.y;
  int bx = blockIdx.x * 32, by = blockIdx.y * 32;
  t[ty][tx] = W[(size_t)(by + ty) * D + bx + tx];
  __syncthreads();
  Wt[(size_t)(bx + ty) * D + by + tx] = f2bf(t[tx][ty]);
}

// fused-q weight: Wt[h*64+d][i] = sum_f Wsrc[i][h*64+f] * R[h][d][f]  (bf16, transposed)
__global__ void fuse_q_kernel(const float* __restrict__ Wsrc, const float* __restrict__ R,
                              unsigned short* __restrict__ Wt) {
  int idx = blockIdx.x * 256 + threadIdx.x;
  if (idx >= D * D) return;
  int i = idx % D;
  int hd = idx / D;
  int h = hd >> 6, d = hd & 63;
  const float* wrow = Wsrc + (size_t)i * D + h * 64;
  const float* rrow = R + ((size_t)h * 64 + d) * 64;
  float s = 0.f;
#pragma unroll 16
  for (int f = 0; f < 64; ++f) s += wrow[f] * rrow[f];
  Wt[idx] = f2bf(s);
}

// fused-v weight: Wt[h*64+f][i] = sum_d Wsrc[i][h*64+d] * M[h][d][f]
__global__ void fuse_v_kernel(const float* __restrict__ Wsrc, const float* __restrict__ Mrel,
                              unsigned short* __restrict__ Wt) {
  int idx = blockIdx.x * 256 + threadIdx.x;
  if (idx >= D * D) return;
  int i = idx % D;
  int hf = idx / D;
  int h = hf >> 6, f = hf & 63;
  const float* wrow = Wsrc + (size_t)i * D + h * 64;
  const float* mcol = Mrel + (size_t)h * 4096 + f;
  float s = 0.f;
#pragma unroll 16
  for (int d = 0; d < 64; ++d) s += wrow[d] * mcol[d * 64];
  Wt[idx] = f2bf(s);
}

__global__ void fuse_qb_kernel(const float* __restrict__ qb, const float* __restrict__ R,
                               float* __restrict__ out) {
  int hd = blockIdx.x * 256 + threadIdx.x;
  if (hd >= D) return;
  int h = hd >> 6, d = hd & 63;
  const float* rrow = R + ((size_t)h * 64 + d) * 64;
  float s = 0.f;
  for (int f = 0; f < 64; ++f) s += qb[h * 64 + f] * rrow[f];
  out[hd] = s;
}

__global__ void fuse_vb_kernel(const float* __restrict__ vb, const float* __restrict__ Mrel,
                               float* __restrict__ out) {
  int hf = blockIdx.x * 256 + threadIdx.x;
  if (hf >= D) return;
  int h = hf >> 6, f = hf & 63;
  float s = 0.f;
  for (int d = 0; d < 64; ++d) s += vb[h * 64 + d] * Mrel[(size_t)h * 4096 + d * 64 + f];
  out[hf] = s;
}

// ---------------- CSR build ----------------
__global__ void count_kernel(const int* __restrict__ dst, int* __restrict__ deg, int E) {
  int e = blockIdx.x * blockDim.x + threadIdx.x;
  if (e < E) atomicAdd(&deg[dst[e]], 1);
}

__global__ void scan_kernel(const int* __restrict__ deg, int* __restrict__ off, int N) {
  __shared__ int tmp[1024];
  __shared__ int carry;
  int tid = threadIdx.x;
  if (tid == 0) carry = 0;
  __syncthreads();
  for (int base = 0; base < N; base += 1024) {
    int i = base + tid;
    int v = (i < N) ? deg[i] : 0;
    tmp[tid] = v;
    __syncthreads();
    for (int s = 1; s < 1024; s <<= 1) {
      int t2 = (tid >= s) ? tmp[tid - s] : 0;
      __syncthreads();
      tmp[tid] += t2;
      __syncthreads();
    }
    int inc = tmp[tid];
    int c = carry;
    if (i < N) off[i] = c + inc - v;
    int tot = tmp[1023];
    __syncthreads();
    if (tid == 0) carry = c + tot;
    __syncthreads();
  }
  if (tid == 0) off[N] = carry;
}

__global__ void scatter_kernel(const int* __restrict__ dst, const int* __restrict__ src,
                               const int* __restrict__ off, int* __restrict__ cur,
                               int* __restrict__ elist, int E) {
  int e = blockIdx.x * blockDim.x + threadIdx.x;
  if (e >= E) return;
  int d = dst[e];
  int slot = off[d] + atomicAdd(&cur[d], 1);
  elist[slot] = src[e];
}

// ---------------- fused per-dst attention (online softmax) ----------------
// one wave per dst node; lane = head-dim. writes gelu(agg) as bf16.
__global__ void attn_kernel(const unsigned short* __restrict__ kb,
                            const unsigned short* __restrict__ tqb,
                            const unsigned short* __restrict__ vmb,
                            const int* __restrict__ off, const int* __restrict__ elist,
                            const float* __restrict__ prel,
                            unsigned short* __restrict__ aggb, int N) {
  int node = blockIdx.x * 4 + (threadIdx.x >> 6);
  int lane = threadIdx.x & 63;
  if (node >= N) return;
  int e0 = off[node], e1 = off[node + 1];
  float tq[H], pr8[H], m[H], den[H], acc[H];
#pragma unroll
  for (int h = 0; h < H; ++h) {
    tq[h] = bf2f(tqb[(size_t)node * D + h * DH + lane]);
    pr8[h] = prel[h] * 0.125f;
    m[h] = -1e30f; den[h] = 0.f; acc[h] = 0.f;
  }
  for (int i = e0; i < e1; ++i) {
    int s = elist[i];
    const unsigned short* kp = kb + (size_t)s * D;
    const unsigned short* vp = vmb + (size_t)s * D;
    float sc[H];
#pragma unroll
    for (int h = 0; h < H; ++h) sc[h] = bf2f(kp[h * DH + lane]) * tq[h];
#pragma unroll
    for (int o = 32; o; o >>= 1)
#pragma unroll
      for (int h = 0; h < H; ++h) sc[h] += __shfl_xor(sc[h], o);
#pragma unroll
    for (int h = 0; h < H; ++h) {
      float v = sc[h] * pr8[h];
      float mn = fmaxf(m[h], v);
      float r = expf(m[h] - mn);
      float p = expf(v - mn);
      den[h] = den[h] * r + p;
      acc[h] = acc[h] * r + p * bf2f(vp[h * DH + lane]);
      m[h] = mn;
    }
  }
  unsigned short* op = aggb + (size_t)node * D;
#pragma unroll
  for (int h = 0; h < H; ++h) {
    float o = (e1 > e0) ? acc[h] / den[h] : 0.f;
    op[h * DH + lane] = f2bf(geluf(o));
  }
}

// ---------------- MFMA bf16 GEMM: C[M,384] = A[M,384] @ W, Wt[n][k] transposed ----------------
// 256 threads = 4 waves (2x2), BM=128, BN=64. B staged full-K in LDS (swizzled),
// A double-buffered per 64-K-step via global_load_lds (source-pre-swizzled, linear dest).
__global__ __launch_bounds__(256) void gemm_bf16(
    const unsigned short* __restrict__ A, const unsigned short* __restrict__ Wt,
    const float* __restrict__ bias, float* __restrict__ Cf,
    unsigned short* __restrict__ Cb, int M, int relu,
    const float* __restrict__ xold, const float* __restrict__ skipPtr) {
  __shared__ unsigned short Bs[64 * 384];     // [col][k] swizzled, 48 KB
  __shared__ unsigned short As[2][128 * 64];  // [row][k] swizzled, 2x16 KB
  const int tid = threadIdx.x;
  const int w = tid >> 6, lane = tid & 63;
  const int bm = blockIdx.x * 128, bn = blockIdx.y * 64;

  // stage B (all 384 K): thread t handles col=t&63, chunks [(t>>6)*12, +12)
  {
    const int col = tid & 63;
    const int cg0 = (tid >> 6) * 12;
    const unsigned short* wp = Wt + (size_t)(bn + col) * D;
#pragma unroll
    for (int c = 0; c < 12; ++c) {
      int cg = cg0 + c;
      uint4 dreg = *(const uint4*)(wp + cg * 8);
      *(uint4*)&Bs[col * D + ((cg ^ (col & 7)) * 8)] = dreg;
    }
  }

  auto stageA = [&](int t, int buf) {
#pragma unroll
    for (int i = 0; i < 4; ++i) {
      int seg = w * 4 + i;                 // 16 segs of 8 rows
      int row = seg * 8 + (lane >> 3);
      int cs = lane & 7;
      int cg = cs ^ (row & 7);             // pre-swizzled global chunk
      int grow = bm + row;
      if (grow >= M) grow = M - 1;
      const unsigned short* gp = A + (size_t)grow * D + t * 64 + cg * 8;
      unsigned short* lp = &As[buf][seg * 512];  // + lane*16B implicit
      __builtin_amdgcn_global_load_lds((const __attribute__((address_space(1))) void*)gp,
                                       (__attribute__((address_space(3))) void*)lp, 16, 0, 0);
    }
  };

  stageA(0, 0);
  __syncthreads();

  const int wr = w >> 1, wc = w & 1;
  const int la = lane & 15, hi = lane >> 4;
  f32x4 acc[4][2] = {};

  for (int t = 0; t < 6; ++t) {
    if (t < 5) stageA(t + 1, (t + 1) & 1);
    const unsigned short* Ab = As[t & 1];
#pragma unroll
    for (int ks = 0; ks < 2; ++ks) {
      short8 af[4], bf[2];
#pragma unroll
      for (int m = 0; m < 4; ++m) {
        int row = wr * 64 + m * 16 + la;
        int c = ks * 4 + hi;
        af[m] = *(const short8*)&Ab[row * 64 + ((c ^ (row & 7)) * 8)];
      }
#pragma unroll
      for (int n = 0; n < 2; ++n) {
        int col = wc * 32 + n * 16 + la;
        int c = t * 8 + ks * 4 + hi;
        bf[n] = *(const short8*)&Bs[col * D + ((c ^ (col & 7)) * 8)];
      }
#pragma unroll
      for (int m = 0; m < 4; ++m)
#pragma unroll
        for (int n = 0; n < 2; ++n)
          acc[m][n] = __builtin_amdgcn_mfma_f32_16x16x32_bf16(af[m], bf[n], acc[m][n], 0, 0, 0);
    }
    __syncthreads();
  }

  float sa = 0.f;
  if (xold) sa = 1.0f / (1.0f + expf(-*skipPtr));
#pragma unroll
  for (int m = 0; m < 4; ++m) {
#pragma unroll
    for (int n = 0; n < 2; ++n) {
#pragma unroll
      for (int r = 0; r < 4; ++r) {
        int row = bm + wr * 64 + m * 16 + hi * 4 + r;
        int col = bn + wc * 32 + n * 16 + la;
        if (row >= M) continue;
        float v = acc[m][n][r] + bias[col];
        if (relu) v = fmaxf(v, 0.f);
        if (xold) v = sa * v + (1.0f - sa) * xold[(size_t)row * D + col];
        if (Cf) Cf[(size_t)row * D + col] = v;
        if (Cb) Cb[(size_t)row * D + col] = f2bf(v);
      }
    }
  }
}

extern "C" void kernel_launch(void* const* d_in, const int* in_sizes, int n_in,
                              void* d_out, int out_size, void* d_ws, size_t ws_size,
                              hipStream_t stream) {
  const float* tok_msg = (const float*)d_in[0];
  const float* tok_con = (const float*)d_in[1];
  const int* ids_msg = (const int*)d_in[2];
  const int* ids_con = (const int*)d_in[3];
  const int* src_cm = (const int*)d_in[4];
  const int* dst_cm = (const int*)d_in[5];
  const int* src_mc = (const int*)d_in[6];
  const int* dst_mc = (const int*)d_in[7];
  const float* lin_W = (const float*)d_in[8];
  const float* lin_b = (const float*)d_in[9];
  const float* kW = (const float*)d_in[10];
  const float* kb = (const float*)d_in[11];
  const float* qW = (const float*)d_in[12];
  const float* qb = (const float*)d_in[13];
  const float* vW = (const float*)d_in[14];
  const float* vb = (const float*)d_in[15];
  const float* aW = (const float*)d_in[16];
  const float* ab = (const float*)d_in[17];
  const float* a_rel = (const float*)d_in[18];
  const float* m_rel = (const float*)d_in[19];
  const float* p_rel = (const float*)d_in[20];
  const float* skip = (const float*)d_in[21];

  const int NM = in_sizes[2] / L;
  const int NC = in_sizes[3] / L;
  const int E = in_sizes[4];
  const size_t WSZ = (size_t)D * D;
  const size_t RSZ = (size_t)H * DH * DH;

  char* wsb = (char*)d_ws;
  size_t woff = 0;
  auto alloc = [&](size_t bytes) {
    woff = (woff + 255) & ~(size_t)255;
    void* p = wsb + woff;
    woff += bytes;
    return p;
  };
  const size_t NMb = (size_t)NM * D, NCb = (size_t)NC * D;
  unsigned short* poolM = (unsigned short*)alloc(NMb * 2);
  unsigned short* poolC = (unsigned short*)alloc(NCb * 2);
  float* x0f = (float*)alloc(NMb * 4);
  float* x1f = (float*)alloc(NCb * 4);
  float* xn0f = (float*)alloc(NMb * 4);
  float* xn1f = (float*)alloc(NCb * 4);
  unsigned short* x0b = (unsigned short*)alloc(NMb * 2);
  unsigned short* x1b = (unsigned short*)alloc(NCb * 2);
  unsigned short* xn0b = (unsigned short*)alloc(NMb * 2);
  unsigned short* xn1b = (unsigned short*)alloc(NCb * 2);
  unsigned short* kMb = (unsigned short*)alloc(NMb * 2);
  unsigned short* kCb = (unsigned short*)alloc(NCb * 2);
  unsigned short* tqMb = (unsigned short*)alloc(NMb * 2);
  unsigned short* tqCb = (unsigned short*)alloc(NCb * 2);
  unsigned short* vmCb = (unsigned short*)alloc(NCb * 2);
  unsigned short* vmMb = (unsigned short*)alloc(NMb * 2);
  unsigned short* aggMb = (unsigned short*)alloc(NMb * 2);
  unsigned short* aggCb = (unsigned short*)alloc(NCb * 2);
  unsigned short* linT0 = (unsigned short*)alloc(WSZ * 2);
  unsigned short* linT1 = (unsigned short*)alloc(WSZ * 2);
  unsigned short* kT00 = (unsigned short*)alloc(WSZ * 2);
  unsigned short* kT01 = (unsigned short*)alloc(WSZ * 2);
  unsigned short* kT11 = (unsigned short*)alloc(WSZ * 2);
  unsigned short* aT00 = (unsigned short*)alloc(WSZ * 2);
  unsigned short* aT01 = (unsigned short*)alloc(WSZ * 2);
  unsigned short* aT10 = (unsigned short*)alloc(WSZ * 2);
  unsigned short* qfT0 = (unsigned short*)alloc(WSZ * 2);
  unsigned short* qfT1 = (unsigned short*)alloc(WSZ * 2);
  unsigned short* qfT2 = (unsigned short*)alloc(WSZ * 2);
  unsigned short* vfT0 = (unsigned short*)alloc(WSZ * 2);
  unsigned short* vfT1 = (unsigned short*)alloc(WSZ * 2);
  unsigned short* vfT2 = (unsigned short*)alloc(WSZ * 2);
  float* qbf0 = (float*)alloc(D * 4);
  float* qbf1 = (float*)alloc(D * 4);
  float* qbf2 = (float*)alloc(D * 4);
  float* vbf0 = (float*)alloc(D * 4);
  float* vbf1 = (float*)alloc(D * 4);
  float* vbf2 = (float*)alloc(D * 4);
  int* deg0 = (int*)alloc((size_t)NM * 4);
  int* off0 = (int*)alloc((size_t)(NM + 1) * 4);
  int* cur0 = (int*)alloc((size_t)NM * 4);
  int* el0 = (int*)alloc((size_t)E * 4);
  int* deg1 = (int*)alloc((size_t)NC * 4);
  int* off1 = (int*)alloc((size_t)(NC + 1) * 4);
  int* cur1 = (int*)alloc((size_t)NC * 4);
  int* el1 = (int*)alloc((size_t)E * 4);

  dim3 b256(256);
  dim3 wtg(12, 12), wtb(32, 32);
  auto gg = [](int M) { return dim3((M + 127) / 128, D / 64); };

  // ---- weight prep ----
  wtconv_kernel<<<wtg, wtb, 0, stream>>>(lin_W, linT0);
  wtconv_kernel<<<wtg, wtb, 0, stream>>>(lin_W + WSZ, linT1);
  wtconv_kernel<<<wtg, wtb, 0, stream>>>(kW + 0 * WSZ, kT00);
  wtconv_kernel<<<wtg, wtb, 0, stream>>>(kW + 1 * WSZ, kT01);
  wtconv_kernel<<<wtg, wtb, 0, stream>>>(kW + 3 * WSZ, kT11);
  wtconv_kernel<<<wtg, wtb, 0, stream>>>(aW + 0 * WSZ, aT00);
  wtconv_kernel<<<wtg, wtb, 0, stream>>>(aW + 1 * WSZ, aT01);
  wtconv_kernel<<<wtg, wtb, 0, stream>>>(aW + 2 * WSZ, aT10);
  int fg = (D * D + 255) / 256;
  fuse_q_kernel<<<fg, b256, 0, stream>>>(qW + 0 * WSZ, a_rel + 0 * RSZ, qfT0);
  fuse_q_kernel<<<fg, b256, 0, stream>>>(qW + 1 * WSZ, a_rel + 1 * RSZ, qfT1);
  fuse_q_kernel<<<fg, b256, 0, stream>>>(qW + 2 * WSZ, a_rel + 2 * RSZ, qfT2);
  fuse_v_kernel<<<fg, b256, 0, stream>>>(vW + 1 * WSZ, m_rel + 0 * RSZ, vfT0);
  fuse_v_kernel<<<fg, b256, 0, stream>>>(vW + 0 * WSZ, m_rel + 1 * RSZ, vfT1);
  fuse_v_kernel<<<fg, b256, 0, stream>>>(vW + 3 * WSZ, m_rel + 2 * RSZ, vfT2);
  fuse_qb_kernel<<<2, b256, 0, stream>>>(qb + 0 * D, a_rel + 0 * RSZ, qbf0);
  fuse_qb_kernel<<<2, b256, 0, stream>>>(qb + 1 * D, a_rel + 1 * RSZ, qbf1);
  fuse_qb_kernel<<<2, b256, 0, stream>>>(qb + 2 * D, a_rel + 2 * RSZ, qbf2);
  fuse_vb_kernel<<<2, b256, 0, stream>>>(vb + 1 * D, m_rel + 0 * RSZ, vbf0);
  fuse_vb_kernel<<<2, b256, 0, stream>>>(vb + 0 * D, m_rel + 1 * RSZ, vbf1);
  fuse_vb_kernel<<<2, b256, 0, stream>>>(vb + 3 * D, m_rel + 2 * RSZ, vbf2);

  // ---- CSR build (edges constant across layers) ----
  int eg = (E + 255) / 256;
  fill_kernel<<<64, b256, 0, stream>>>((float*)deg0, NM, 0.f);
  count_kernel<<<eg, b256, 0, stream>>>(dst_cm, deg0, E);
  scan_kernel<<<1, 1024, 0, stream>>>(deg0, off0, NM);
  fill_kernel<<<64, b256, 0, stream>>>((float*)cur0, NM, 0.f);
  scatter_kernel<<<eg, b256, 0, stream>>>(dst_cm, src_cm, off0, cur0, el0, E);
  fill_kernel<<<64, b256, 0, stream>>>((float*)deg1, NC, 0.f);
  count_kernel<<<eg, b256, 0, stream>>>(dst_mc, deg1, E);
  scan_kernel<<<1, 1024, 0, stream>>>(deg1, off1, NC);
  fill_kernel<<<64, b256, 0, stream>>>((float*)cur1, NC, 0.f);
  scatter_kernel<<<eg, b256, 0, stream>>>(dst_mc, src_mc, off1, cur1, el1, E);

  // ---- pooling + initial linear ----
  pool_norm_kernel<<<NM, D, 0, stream>>>(tok_msg, ids_msg, poolM, NM);
  pool_norm_kernel<<<NC, D, 0, stream>>>(tok_con, ids_con, poolC, NC);
  gemm_bf16<<<gg(NM), b256, 0, stream>>>(poolM, linT0, lin_b, x0f, x0b, NM, 1, nullptr, nullptr);
  gemm_bf16<<<gg(NC), b256, 0, stream>>>(poolC, linT1, lin_b + D, x1f, x1b, NC, 1, nullptr, nullptr);

  // ---- layer 1 ----
  gemm_bf16<<<gg(NC), b256, 0, stream>>>(x1b, kT01, kb + 1 * D, nullptr, kCb, NC, 0, nullptr, nullptr);
  gemm_bf16<<<gg(NM), b256, 0, stream>>>(x0b, kT00, kb + 0 * D, nullptr, kMb, NM, 0, nullptr, nullptr);
  gemm_bf16<<<gg(NM), b256, 0, stream>>>(x0b, qfT0, qbf0, nullptr, tqMb, NM, 0, nullptr, nullptr);
  gemm_bf16<<<gg(NC), b256, 0, stream>>>(x1b, qfT1, qbf1, nullptr, tqCb, NC, 0, nullptr, nullptr);
  gemm_bf16<<<gg(NC), b256, 0, stream>>>(x1b, vfT0, vbf0, nullptr, vmCb, NC, 0, nullptr, nullptr);
  gemm_bf16<<<gg(NM), b256, 0, stream>>>(x0b, vfT1, vbf1, nullptr, vmMb, NM, 0, nullptr, nullptr);
  attn_kernel<<<(NM + 3) / 4, b256, 0, stream>>>(kCb, tqMb, vmCb, off0, el0, p_rel + 0 * H, aggMb, NM);
  attn_kernel<<<(NC + 3) / 4, b256, 0, stream>>>(kMb, tqCb, vmMb, off1, el1, p_rel + 1 * H, aggCb, NC);
  gemm_bf16<<<gg(NM), b256, 0, stream>>>(aggMb, aT00, ab + 0 * D, xn0f, xn0b, NM, 0, x0f, skip + 0);
  gemm_bf16<<<gg(NC), b256, 0, stream>>>(aggCb, aT01, ab + 1 * D, xn1f, xn1b, NC, 0, x1f, skip + 1);

  // ---- layer 2 (only xs[0] needed downstream) ----
  gemm_bf16<<<gg(NC), b256, 0, stream>>>(xn1b, kT11, kb + 3 * D, nullptr, kCb, NC, 0, nullptr, nullptr);
  gemm_bf16<<<gg(NM), b256, 0, stream>>>(xn0b, qfT2, qbf2, nullptr, tqMb, NM, 0, nullptr, nullptr);
  gemm_bf16<<<gg(NC), b256, 0, stream>>>(xn1b, vfT2, vbf2, nullptr, vmCb, NC, 0, nullptr, nullptr);
  attn_kernel<<<(NM + 3) / 4, b256, 0, stream>>>(kCb, tqMb, vmCb, off0, el0, p_rel + 2 * H, aggMb, NM);
  gemm_bf16<<<gg(NM), b256, 0, stream>>>(aggMb, aT10, ab + 2 * D, (float*)d_out, nullptr, NM, 0, xn0f, skip + 2);
}

// Round 4
// 713.756 us; speedup vs baseline: 3.7549x; 1.4344x over previous
//
#include <hip/hip_runtime.h>
#include <math.h>

#define H 6
#define DH 64
#define D 384
#define L 16
#define WSZ ((size_t)(D) * (D))
#define RSZ ((size_t)(H) * (DH) * (DH))

typedef __attribute__((ext_vector_type(8))) short short8;
typedef __attribute__((ext_vector_type(4))) float f32x4;

__device__ __forceinline__ float bf2f(unsigned short u) {
  union { unsigned int i; float f; } x; x.i = ((unsigned int)u) << 16; return x.f;
}
__device__ __forceinline__ unsigned short f2bf(float f) {
  unsigned int x = __float_as_uint(f);
  x = x + 0x7fffu + ((x >> 16) & 1u);
  return (unsigned short)(x >> 16);
}
__device__ __forceinline__ float geluf(float x) {
  return 0.5f * x * (1.0f + erff(x * 0.70710678118654752f));
}

__global__ void zero_int_kernel(int* p, long n) {
  long i = (long)blockIdx.x * blockDim.x + threadIdx.x;
  long stride = (long)gridDim.x * blockDim.x;
  for (; i < n; i += stride) p[i] = 0;
}

// masked mean pool over L tokens then L2 normalize -> bf16. one block per node, 384 threads.
__global__ void pool_norm_kernel(const float* __restrict__ tok, const int* __restrict__ ids,
                                 unsigned short* __restrict__ out, int N) {
  int n = blockIdx.x;
  int t = threadIdx.x;
  const float* tp = tok + (size_t)n * L * D;
  const int* ip = ids + (size_t)n * L;
  float s = 0.f;
  int cnt = 0;
#pragma unroll
  for (int l = 0; l < L; ++l) {
    int m = (ip[l] > 0);
    cnt += m;
    s += tp[(size_t)l * D + t] * (float)m;
  }
  float mean = s / fmaxf((float)cnt, 1e-9f);
  float v = mean * mean;
#pragma unroll
  for (int off = 32; off; off >>= 1) v += __shfl_down(v, off);
  __shared__ float part[D / 64];
  if ((t & 63) == 0) part[t >> 6] = v;
  __syncthreads();
  float tot = 0.f;
#pragma unroll
  for (int i = 0; i < D / 64; ++i) tot += part[i];
  float inv = 1.0f / fmaxf(sqrtf(tot), 1e-12f);
  out[(size_t)n * D + t] = f2bf(mean * inv);
}

// ---- unified weight prep: 14 slots of [384 n][384 k] bf16 in wbuf ----
// type 0: transpose fp32 W[k][n] -> Wt[n][k]
// type 1: fuse_q: Wt[h*64+d][k] = sum_f W[k][h*64+f] * A[h][d][f]
// type 2: fuse_v: Wt[h*64+f][k] = sum_d W[k][h*64+d] * M[h][d][f]
__global__ void prepw_kernel(const float* __restrict__ lin_W, const float* __restrict__ kW,
                             const float* __restrict__ qW, const float* __restrict__ vW,
                             const float* __restrict__ aW, const float* __restrict__ a_rel,
                             const float* __restrict__ m_rel, unsigned short* __restrict__ wbuf) {
  int z = blockIdx.z;
  const float* src; const float* rel = nullptr; int type = 0;
  switch (z) {
    case 0: src = lin_W; break;
    case 1: src = lin_W + WSZ; break;
    case 2: src = kW; break;
    case 3: type = 1; src = qW; rel = a_rel; break;
    case 4: type = 2; src = vW; rel = m_rel + RSZ; break;
    case 5: src = kW + WSZ; break;
    case 6: type = 1; src = qW + WSZ; rel = a_rel + RSZ; break;
    case 7: type = 2; src = vW + WSZ; rel = m_rel; break;
    case 8: type = 1; src = qW + 2 * WSZ; rel = a_rel + 2 * RSZ; break;
    case 9: src = kW + 3 * WSZ; break;
    case 10: type = 2; src = vW + 3 * WSZ; rel = m_rel + 2 * RSZ; break;
    case 11: src = aW; break;
    case 12: src = aW + WSZ; break;
    default: src = aW + 2 * WSZ; break;
  }
  unsigned short* dst = wbuf + (size_t)z * WSZ;
  int tx = threadIdx.x, ty = threadIdx.y;
  int bx = blockIdx.x * 32;  // k range
  int by = blockIdx.y * 32;  // n range
  if (type == 0) {
    __shared__ float tile[32][33];
    tile[ty][tx] = src[(size_t)(bx + ty) * D + by + tx];
    __syncthreads();
    dst[(size_t)(by + ty) * D + bx + tx] = f2bf(tile[tx][ty]);
  } else if (type == 1) {
    int h = by >> 6, d0 = by & 63;
    __shared__ float Wt_[32][65], Rt[32][65];
#pragma unroll
    for (int half = 0; half < 2; ++half) {
      Wt_[ty][tx + half * 32] = src[(size_t)(bx + ty) * D + h * 64 + tx + half * 32];
      Rt[ty][tx + half * 32] = rel[(size_t)h * 4096 + (size_t)(d0 + ty) * 64 + tx + half * 32];
    }
    __syncthreads();
    float s = 0.f;
#pragma unroll 16
    for (int f = 0; f < 64; ++f) s += Wt_[tx][f] * Rt[ty][f];
    dst[(size_t)(by + ty) * D + bx + tx] = f2bf(s);
  } else {
    int h = by >> 6, f0 = by & 63;
    __shared__ float Wt_[32][65];
    __shared__ float Mt[64][33];
#pragma unroll
    for (int half = 0; half < 2; ++half) {
      Wt_[ty][tx + half * 32] = src[(size_t)(bx + ty) * D + h * 64 + tx + half * 32];
      Mt[ty * 2 + half][tx] = rel[(size_t)h * 4096 + (size_t)(ty * 2 + half) * 64 + f0 + tx];
    }
    __syncthreads();
    float s = 0.f;
#pragma unroll 16
    for (int d = 0; d < 64; ++d) s += Wt_[tx][d] * Mt[d][ty];
    dst[(size_t)(by + ty) * D + bx + tx] = f2bf(s);
  }
}

// fused bias vector: [bM1(1152) | bC1(1152) | bM2(384) | bC2(768)]
__global__ void prepb_kernel(const float* __restrict__ kb, const float* __restrict__ qb,
                             const float* __restrict__ vb, const float* __restrict__ a_rel,
                             const float* __restrict__ m_rel, float* __restrict__ bbuf) {
  int i = blockIdx.x * 256 + threadIdx.x;
  if (i >= 3456) return;
  int gemm, col;
  if (i < 1152) { gemm = 0; col = i; }
  else if (i < 2304) { gemm = 1; col = i - 1152; }
  else if (i < 2688) { gemm = 2; col = i - 2304; }
  else { gemm = 3; col = i - 2688; }
  int sec = col / D, j = col % D, h = j >> 6, r = j & 63;
  float out = 0.f;
  if (gemm == 0) {
    if (sec == 0) out = kb[j];
    else if (sec == 1) {
      const float* R = a_rel + (size_t)h * 4096 + (size_t)r * 64;
      float s = 0.f; for (int f = 0; f < 64; ++f) s += qb[h * 64 + f] * R[f]; out = s;
    } else {
      const float* Mm = m_rel + RSZ + (size_t)h * 4096;
      float s = 0.f; for (int d = 0; d < 64; ++d) s += vb[h * 64 + d] * Mm[d * 64 + r]; out = s;
    }
  } else if (gemm == 1) {
    if (sec == 0) out = kb[D + j];
    else if (sec == 1) {
      const float* R = a_rel + RSZ + (size_t)h * 4096 + (size_t)r * 64;
      float s = 0.f; for (int f = 0; f < 64; ++f) s += qb[D + h * 64 + f] * R[f]; out = s;
    } else {
      const float* Mm = m_rel + (size_t)h * 4096;
      float s = 0.f; for (int d = 0; d < 64; ++d) s += vb[D + h * 64 + d] * Mm[d * 64 + r]; out = s;
    }
  } else if (gemm == 2) {
    const float* R = a_rel + 2 * RSZ + (size_t)h * 4096 + (size_t)r * 64;
    float s = 0.f; for (int f = 0; f < 64; ++f) s += qb[2 * D + h * 64 + f] * R[f]; out = s;
  } else {
    if (sec == 0) out = kb[3 * D + j];
    else {
      const float* Mm = m_rel + 2 * RSZ + (size_t)h * 4096;
      float s = 0.f; for (int d = 0; d < 64; ++d) s += vb[3 * D + h * 64 + d] * Mm[d * 64 + r]; out = s;
    }
  }
  bbuf[i] = out;
}

// ---------------- CSR build (both edge types in one grid) ----------------
__global__ void count2_kernel(const int* __restrict__ d0, const int* __restrict__ d1,
                              int* __restrict__ deg0, int* __restrict__ deg1, int E) {
  int e = blockIdx.x * blockDim.x + threadIdx.x;
  if (e < E) atomicAdd(&deg0[d0[e]], 1);
  else if (e < 2 * E) atomicAdd(&deg1[d1[e - E]], 1);
}

__global__ void scan2_kernel(const int* __restrict__ deg0, int* __restrict__ off0, int N0,
                             const int* __restrict__ deg1, int* __restrict__ off1, int N1) {
  const int* deg = blockIdx.x ? deg1 : deg0;
  int* off = blockIdx.x ? off1 : off0;
  int N = blockIdx.x ? N1 : N0;
  __shared__ int tmp[1024];
  __shared__ int carry;
  int tid = threadIdx.x;
  if (tid == 0) carry = 0;
  __syncthreads();
  for (int base = 0; base < N; base += 1024) {
    int i = base + tid;
    int v = (i < N) ? deg[i] : 0;
    tmp[tid] = v;
    __syncthreads();
    for (int s = 1; s < 1024; s <<= 1) {
      int t2 = (tid >= s) ? tmp[tid - s] : 0;
      __syncthreads();
      tmp[tid] += t2;
      __syncthreads();
    }
    int inc = tmp[tid];
    int c = carry;
    if (i < N) off[i] = c + inc - v;
    int tot = tmp[1023];
    __syncthreads();
    if (tid == 0) carry = c + tot;
    __syncthreads();
  }
  if (tid == 0) off[N] = carry;
}

__global__ void scatter2_kernel(const int* __restrict__ d0, const int* __restrict__ s0,
                                const int* __restrict__ off0, int* __restrict__ cur0,
                                int* __restrict__ el0,
                                const int* __restrict__ d1, const int* __restrict__ s1,
                                const int* __restrict__ off1, int* __restrict__ cur1,
                                int* __restrict__ el1, int E) {
  int e = blockIdx.x * blockDim.x + threadIdx.x;
  if (e < E) {
    int d = d0[e];
    el0[off0[d] + atomicAdd(&cur0[d], 1)] = s0[e];
  } else if (e < 2 * E) {
    int ee = e - E;
    int d = d1[ee];
    el1[off1[d] + atomicAdd(&cur1[d], 1)] = s1[ee];
  }
}

// ---------------- fused per-dst attention, 2-edge unrolled ----------------
__global__ void attn_kernel(const unsigned short* __restrict__ kb, int sk,
                            const unsigned short* __restrict__ tqb, int st,
                            const unsigned short* __restrict__ vmb, int sv,
                            const int* __restrict__ off, const int* __restrict__ elist,
                            const float* __restrict__ prel,
                            unsigned short* __restrict__ aggb, int N) {
  int node = blockIdx.x * 4 + (threadIdx.x >> 6);
  int lane = threadIdx.x & 63;
  if (node >= N) return;
  int e0 = off[node], e1 = off[node + 1];
  float tq[H], pr8[H], m[H], den[H], acc[H];
#pragma unroll
  for (int h = 0; h < H; ++h) {
    tq[h] = bf2f(tqb[(size_t)node * st + h * DH + lane]);
    pr8[h] = prel[h] * 0.125f;
    m[h] = -1e30f; den[h] = 0.f; acc[h] = 0.f;
  }
  int i = e0;
  for (; i + 2 <= e1; i += 2) {
    int s0 = elist[i], s1 = elist[i + 1];
    const unsigned short* k0 = kb + (size_t)s0 * sk;
    const unsigned short* k1 = kb + (size_t)s1 * sk;
    const unsigned short* v0 = vmb + (size_t)s0 * sv;
    const unsigned short* v1 = vmb + (size_t)s1 * sv;
    float sa[H], sb[H], va[H], vb[H];
#pragma unroll
    for (int h = 0; h < H; ++h) {
      sa[h] = bf2f(k0[h * DH + lane]) * tq[h];
      sb[h] = bf2f(k1[h * DH + lane]) * tq[h];
      va[h] = bf2f(v0[h * DH + lane]);
      vb[h] = bf2f(v1[h * DH + lane]);
    }
#pragma unroll
    for (int o = 32; o; o >>= 1)
#pragma unroll
      for (int h = 0; h < H; ++h) {
        sa[h] += __shfl_xor(sa[h], o);
        sb[h] += __shfl_xor(sb[h], o);
      }
#pragma unroll
    for (int h = 0; h < H; ++h) {
      float x0 = sa[h] * pr8[h], x1 = sb[h] * pr8[h];
      float mn = fmaxf(m[h], fmaxf(x0, x1));
      float r = __expf(m[h] - mn);
      float p0 = __expf(x0 - mn);
      float p1 = __expf(x1 - mn);
      den[h] = den[h] * r + p0 + p1;
      acc[h] = acc[h] * r + p0 * va[h] + p1 * vb[h];
      m[h] = mn;
    }
  }
  if (i < e1) {
    int s0 = elist[i];
    const unsigned short* k0 = kb + (size_t)s0 * sk;
    const unsigned short* v0 = vmb + (size_t)s0 * sv;
    float sa[H], va[H];
#pragma unroll
    for (int h = 0; h < H; ++h) {
      sa[h] = bf2f(k0[h * DH + lane]) * tq[h];
      va[h] = bf2f(v0[h * DH + lane]);
    }
#pragma unroll
    for (int o = 32; o; o >>= 1)
#pragma unroll
      for (int h = 0; h < H; ++h) sa[h] += __shfl_xor(sa[h], o);
#pragma unroll
    for (int h = 0; h < H; ++h) {
      float x0 = sa[h] * pr8[h];
      float mn = fmaxf(m[h], x0);
      float r = __expf(m[h] - mn);
      float p0 = __expf(x0 - mn);
      den[h] = den[h] * r + p0;
      acc[h] = acc[h] * r + p0 * va[h];
      m[h] = mn;
    }
  }
  unsigned short* op = aggb + (size_t)node * D;
#pragma unroll
  for (int h = 0; h < H; ++h) {
    float o = (e1 > e0) ? acc[h] / den[h] : 0.f;
    op[h * DH + lane] = f2bf(geluf(o));
  }
}

// ---------------- MFMA bf16 GEMM: C[M,N] = A[M,384] @ Wt^T, Wt[n][k] ----------------
// BM=BN=128, BK=64, 512 threads = 8 waves (2x4). A and B both staged per-K-step via
// global_load_lds (linear LDS dest, pre-swizzled global source). LDS 64KB -> 2 blocks/CU.
__global__ __launch_bounds__(512) void gemm_bf16(
    const unsigned short* __restrict__ A, const unsigned short* __restrict__ Wt,
    const float* __restrict__ bias, float* __restrict__ Cf,
    unsigned short* __restrict__ Cb, int M, int cpitch, int relu,
    const float* __restrict__ xold, const float* __restrict__ skipPtr) {
  __shared__ __align__(16) unsigned short As[2][128 * 64];
  __shared__ __align__(16) unsigned short Bs[2][128 * 64];
  const int tid = threadIdx.x;
  const int w = tid >> 6, lane = tid & 63;
  const int bm = blockIdx.x * 128, bn = blockIdx.y * 128;

  auto stageA = [&](int t, int buf) {
#pragma unroll
    for (int i = 0; i < 2; ++i) {
      int cid = (w * 2 + i) * 64 + lane;
      int row = cid >> 3;
      int cg = (cid & 7) ^ (row & 7);
      int grow = bm + row;
      if (grow >= M) grow = M - 1;
      const unsigned short* gp = A + (size_t)grow * D + t * 64 + cg * 8;
      unsigned short* lp = &As[buf][(w * 2 + i) * 512];
      __builtin_amdgcn_global_load_lds((const __attribute__((address_space(1))) void*)gp,
                                       (__attribute__((address_space(3))) void*)lp, 16, 0, 0);
    }
  };
  auto stageB = [&](int t, int buf) {
#pragma unroll
    for (int i = 0; i < 2; ++i) {
      int cid = (w * 2 + i) * 64 + lane;
      int row = cid >> 3;
      int cg = (cid & 7) ^ (row & 7);
      const unsigned short* gp = Wt + (size_t)(bn + row) * D + t * 64 + cg * 8;
      unsigned short* lp = &Bs[buf][(w * 2 + i) * 512];
      __builtin_amdgcn_global_load_lds((const __attribute__((address_space(1))) void*)gp,
                                       (__attribute__((address_space(3))) void*)lp, 16, 0, 0);
    }
  };

  stageA(0, 0);
  stageB(0, 0);
  __syncthreads();

  const int wr = w >> 2, wc = w & 3;
  const int la = lane & 15, hi = lane >> 4;
  f32x4 acc[4][2] = {};

  for (int t = 0; t < 6; ++t) {
    if (t < 5) {
      stageA(t + 1, (t + 1) & 1);
      stageB(t + 1, (t + 1) & 1);
    }
    const unsigned short* Ab = As[t & 1];
    const unsigned short* Bb = Bs[t & 1];
#pragma unroll
    for (int ks = 0; ks < 2; ++ks) {
      int c = ks * 4 + hi;
      short8 af[4], bfr[2];
#pragma unroll
      for (int mi = 0; mi < 4; ++mi) {
        int row = wr * 64 + mi * 16 + la;
        af[mi] = *(const short8*)&Ab[row * 64 + ((c ^ (row & 7)) * 8)];
      }
#pragma unroll
      for (int n = 0; n < 2; ++n) {
        int col = wc * 32 + n * 16 + la;
        bfr[n] = *(const short8*)&Bb[col * 64 + ((c ^ (col & 7)) * 8)];
      }
#pragma unroll
      for (int mi = 0; mi < 4; ++mi)
#pragma unroll
        for (int n = 0; n < 2; ++n)
          acc[mi][n] = __builtin_amdgcn_mfma_f32_16x16x32_bf16(af[mi], bfr[n], acc[mi][n], 0, 0, 0);
    }
    __syncthreads();
  }

  float sa = 0.f;
  if (xold) sa = 1.0f / (1.0f + __expf(-*skipPtr));
#pragma unroll
  for (int mi = 0; mi < 4; ++mi) {
#pragma unroll
    for (int n = 0; n < 2; ++n) {
#pragma unroll
      for (int r = 0; r < 4; ++r) {
        int row = bm + wr * 64 + mi * 16 + hi * 4 + r;
        int col = bn + wc * 32 + n * 16 + la;
        if (row >= M) continue;
        float v = acc[mi][n][r] + bias[col];
        if (relu) v = fmaxf(v, 0.f);
        if (xold) v = sa * v + (1.0f - sa) * xold[(size_t)row * D + col];
        if (Cf) Cf[(size_t)row * cpitch + col] = v;
        if (Cb) Cb[(size_t)row * cpitch + col] = f2bf(v);
      }
    }
  }
}

extern "C" void kernel_launch(void* const* d_in, const int* in_sizes, int n_in,
                              void* d_out, int out_size, void* d_ws, size_t ws_size,
                              hipStream_t stream) {
  const float* tok_msg = (const float*)d_in[0];
  const float* tok_con = (const float*)d_in[1];
  const int* ids_msg = (const int*)d_in[2];
  const int* ids_con = (const int*)d_in[3];
  const int* src_cm = (const int*)d_in[4];
  const int* dst_cm = (const int*)d_in[5];
  const int* src_mc = (const int*)d_in[6];
  const int* dst_mc = (const int*)d_in[7];
  const float* lin_W = (const float*)d_in[8];
  const float* lin_b = (const float*)d_in[9];
  const float* kW = (const float*)d_in[10];
  const float* kb = (const float*)d_in[11];
  const float* qW = (const float*)d_in[12];
  const float* qb = (const float*)d_in[13];
  const float* vW = (const float*)d_in[14];
  const float* vb = (const float*)d_in[15];
  const float* aW = (const float*)d_in[16];
  const float* ab = (const float*)d_in[17];
  const float* a_rel = (const float*)d_in[18];
  const float* m_rel = (const float*)d_in[19];
  const float* p_rel = (const float*)d_in[20];
  const float* skip = (const float*)d_in[21];

  const int NM = in_sizes[2] / L;
  const int NC = in_sizes[3] / L;
  const int E = in_sizes[4];

  char* wsb = (char*)d_ws;
  size_t woff = 0;
  auto alloc = [&](size_t bytes) {
    woff = (woff + 255) & ~(size_t)255;
    void* p = wsb + woff;
    woff += bytes;
    return p;
  };
  const size_t NMe = (size_t)NM * D, NCe = (size_t)NC * D;
  unsigned short* poolM = (unsigned short*)alloc(NMe * 2);
  unsigned short* poolC = (unsigned short*)alloc(NCe * 2);
  float* x0f = (float*)alloc(NMe * 4);
  float* x1f = (float*)alloc(NCe * 4);
  float* xn0f = (float*)alloc(NMe * 4);
  unsigned short* x0b = (unsigned short*)alloc(NMe * 2);
  unsigned short* x1b = (unsigned short*)alloc(NCe * 2);
  unsigned short* xn0b = (unsigned short*)alloc(NMe * 2);
  unsigned short* xn1b = (unsigned short*)alloc(NCe * 2);
  unsigned short* projM1 = (unsigned short*)alloc((size_t)NM * 1152 * 2);
  unsigned short* projC1 = (unsigned short*)alloc((size_t)NC * 1152 * 2);
  unsigned short* projM2 = (unsigned short*)alloc((size_t)NM * 384 * 2);
  unsigned short* projC2 = (unsigned short*)alloc((size_t)NC * 768 * 2);
  unsigned short* aggM = (unsigned short*)alloc(NMe * 2);
  unsigned short* aggC = (unsigned short*)alloc(NCe * 2);
  unsigned short* wbuf = (unsigned short*)alloc(14 * WSZ * 2);
  float* bbuf = (float*)alloc(3456 * 4);
  // CSR integer arrays: ONE contiguous block, hand-sliced (no per-array padding!)
  // layout: [deg0 NM | cur0 NM | deg1 NC | cur1 NC | off0 NM+1 | off1 NC+1 | el0 E | el1 E]
  long nz = 2L * NM + 2L * NC;  // prefix that must be zeroed every launch
  int* ibase = (int*)alloc((size_t)(nz + NM + 1 + NC + 1 + 2L * E) * 4);
  int* deg0 = ibase;
  int* cur0 = deg0 + NM;
  int* deg1 = cur0 + NM;
  int* cur1 = deg1 + NC;
  int* off0 = cur1 + NC;
  int* off1 = off0 + NM + 1;
  int* el0 = off1 + NC + 1;
  int* el1 = el0 + E;

  dim3 b256(256), b512(512);
  auto gg = [](int M, int N) { return dim3((M + 127) / 128, N / 128); };

  // weight & bias prep
  prepw_kernel<<<dim3(12, 12, 14), dim3(32, 32), 0, stream>>>(lin_W, kW, qW, vW, aW, a_rel, m_rel, wbuf);
  prepb_kernel<<<14, b256, 0, stream>>>(kb, qb, vb, a_rel, m_rel, bbuf);

  // CSR build (deg/cur zeroed every launch -> deterministic under graph replay)
  zero_int_kernel<<<64, b256, 0, stream>>>(ibase, nz);
  int eg2 = (2 * E + 255) / 256;
  count2_kernel<<<eg2, b256, 0, stream>>>(dst_cm, dst_mc, deg0, deg1, E);
  scan2_kernel<<<2, 1024, 0, stream>>>(deg0, off0, NM, deg1, off1, NC);
  scatter2_kernel<<<eg2, b256, 0, stream>>>(dst_cm, src_cm, off0, cur0, el0,
                                            dst_mc, src_mc, off1, cur1, el1, E);

  // pooling + initial linear (relu)
  pool_norm_kernel<<<NM, D, 0, stream>>>(tok_msg, ids_msg, poolM, NM);
  pool_norm_kernel<<<NC, D, 0, stream>>>(tok_con, ids_con, poolC, NC);
  gemm_bf16<<<gg(NM, D), b512, 0, stream>>>(poolM, wbuf, lin_b, x0f, x0b, NM, D, 1, nullptr, nullptr);
  gemm_bf16<<<gg(NC, D), b512, 0, stream>>>(poolC, wbuf + WSZ, lin_b + D, x1f, x1b, NC, D, 1, nullptr, nullptr);

  // layer 1: fused k|tq|vm projections
  gemm_bf16<<<gg(NM, 1152), b512, 0, stream>>>(x0b, wbuf + 2 * WSZ, bbuf, nullptr, projM1, NM, 1152, 0, nullptr, nullptr);
  gemm_bf16<<<gg(NC, 1152), b512, 0, stream>>>(x1b, wbuf + 5 * WSZ, bbuf + 1152, nullptr, projC1, NC, 1152, 0, nullptr, nullptr);
  attn_kernel<<<(NM + 3) / 4, b256, 0, stream>>>(projC1, 1152, projM1 + 384, 1152, projC1 + 768, 1152,
                                                 off0, el0, p_rel, aggM, NM);
  attn_kernel<<<(NC + 3) / 4, b256, 0, stream>>>(projM1, 1152, projC1 + 384, 1152, projM1 + 768, 1152,
                                                 off1, el1, p_rel + H, aggC, NC);
  gemm_bf16<<<gg(NM, D), b512, 0, stream>>>(aggM, wbuf + 11 * WSZ, ab, xn0f, xn0b, NM, D, 0, x0f, skip + 0);
  gemm_bf16<<<gg(NC, D), b512, 0, stream>>>(aggC, wbuf + 12 * WSZ, ab + D, nullptr, xn1b, NC, D, 0, x1f, skip + 1);

  // layer 2 (only message output needed)
  gemm_bf16<<<gg(NM, D), b512, 0, stream>>>(xn0b, wbuf + 8 * WSZ, bbuf + 2304, nullptr, projM2, NM, 384, 0, nullptr, nullptr);
  gemm_bf16<<<gg(NC, 768), b512, 0, stream>>>(xn1b, wbuf + 9 * WSZ, bbuf + 2688, nullptr, projC2, NC, 768, 0, nullptr, nullptr);
  attn_kernel<<<(NM + 3) / 4, b256, 0, stream>>>(projC2, 768, projM2, 384, projC2 + 384, 768,
                                                 off0, el0, p_rel + 2 * H, aggM, NM);
  gemm_bf16<<<gg(NM, D), b512, 0, stream>>>(aggM, wbuf + 13 * WSZ, ab + 2 * D, (float*)d_out, nullptr, NM, D, 0, xn0f, skip + 2);
}